// Round 4
// baseline (673.233 us; speedup 1.0000x reference)
//
#include <hip/hip_runtime.h>
#include <math.h>

// VectorQuantizer: argmin_k ||x_n - c_k||^2, N=32768, K=8192, D=64, fp32.
// Expanded form (matches reference): xsq - 2*x.c + csq.
//
// Round-4 structure: x rows resident in VGPRs (RT=1, 64 floats), codebook
// broadcast from LDS. Rounds 2-3 showed the SGPR path is a dead end: a code
// row is 64 SGPRs and the SGPR file caps at ~102, so the next row can never
// be prefetched -> k-loop serializes on scalar-load latency (VALUBusy 52-59%).
// LDS same-address broadcast reads (ds_read_b128) are conflict-free and
// pipeline on lgkmcnt with no SGPR ceiling.
// Register discipline: amdgpu_waves_per_eu(4,4) pins the allocator's
// occupancy target at exactly 4 waves/EU (128-VGPR cap): it can neither
// rematerialize x loads to chase 8 waves (rounds 1-2, VGPR 48/76) nor spill
// pinned values to chase 6 (round 3, VGPR 84 + 111MB scratch writes).
// Tie-break: strict < over ascending k per segment, ascending segment in the
// reducer = numpy first-occurrence. fmaf chains identical to rounds 1-3
// (measured absmax 0).

constexpr int NROWS = 32768;
constexpr int KC    = 8192;
constexpr int DD    = 64;
constexpr int TPB   = 256;
constexpr int TILE  = 128;                    // codes staged per LDS tile
constexpr int ROWBLKS = NROWS / TPB;          // 128

__global__ void csq_kernel(const float* __restrict__ cb, float* __restrict__ csq) {
  const int k = blockIdx.x * blockDim.x + threadIdx.x;
  const float* cp = cb + (size_t)k * DD;
  float s = 0.f;
#pragma unroll
  for (int d = 0; d < DD; ++d) s = fmaf(cp[d], cp[d], s);
  csq[k] = s;
}

__global__ void __launch_bounds__(TPB)
__attribute__((amdgpu_waves_per_eu(4, 4)))
vq_main_kernel(const float* __restrict__ x, const float* __restrict__ cb,
               const float* __restrict__ csq,
               float* __restrict__ segDist, int* __restrict__ segIdx,
               int ksplit) {
  __shared__ alignas(16) float lds_c[TILE * DD];   // 32 KiB
  __shared__ float lds_cs[TILE];                   // 512 B

  const int tid  = threadIdx.x;
  const int seg  = blockIdx.y;
  const int row  = blockIdx.x * TPB + tid;
  const int kseg = KC / ksplit;
  const int kbase = seg * kseg;

  // Load this thread's x row into registers (once).
  float xr[DD];
  const float* xp = x + (size_t)row * DD;
#pragma unroll
  for (int d = 0; d < DD; d += 4) {
    const float4 a = *(const float4*)(xp + d);
    xr[d] = a.x; xr[d + 1] = a.y; xr[d + 2] = a.z; xr[d + 3] = a.w;
  }
  float xsq = 0.f;
#pragma unroll
  for (int d = 0; d < DD; ++d) xsq = fmaf(xr[d], xr[d], xsq);

  // Pin x values in VGPRs (asm results are not rematerializable).
#pragma unroll
  for (int d = 0; d < DD; ++d) asm volatile("" : "+v"(xr[d]));

  float best = INFINITY;
  int   bidx = kbase;

  const int ntiles = kseg / TILE;
  for (int t = 0; t < ntiles; ++t) {
    const int tbase = kbase + t * TILE;
    __syncthreads();
    // Cooperative stage: TILE*DD floats = 2048 float4 = 8 per thread.
    {
      const float4* gsrc = (const float4*)(cb + (size_t)tbase * DD);
      float4* ldst = (float4*)lds_c;
#pragma unroll
      for (int it = 0; it < 8; ++it) {
        const int idx = it * TPB + tid;
        ldst[idx] = gsrc[idx];
      }
      if (tid < TILE) lds_cs[tid] = csq[tbase + tid];
    }
    __syncthreads();

#pragma unroll 2
    for (int j = 0; j < TILE; ++j) {
      const float4* cf4 = (const float4*)(lds_c + j * DD);  // broadcast reads
      float dot = 0.f;
#pragma unroll
      for (int d4 = 0; d4 < DD / 4; ++d4) {
        const float4 c = cf4[d4];
        dot = fmaf(c.x, xr[d4 * 4],     dot);
        dot = fmaf(c.y, xr[d4 * 4 + 1], dot);
        dot = fmaf(c.z, xr[d4 * 4 + 2], dot);
        dot = fmaf(c.w, xr[d4 * 4 + 3], dot);
      }
      const float dist = fmaf(-2.f, dot, xsq) + lds_cs[j];
      if (dist < best) { best = dist; bidx = tbase + j; }  // first k wins ties
    }
  }

  const size_t o = (size_t)seg * NROWS + row;
  segDist[o] = best;
  segIdx[o]  = bidx;
}

__global__ void vq_reduce_kernel(const float* __restrict__ segDist,
                                 const int* __restrict__ segIdx,
                                 int* __restrict__ out, int ksplit) {
  const int n = blockIdx.x * blockDim.x + threadIdx.x;
  float b = INFINITY;
  int  bi = 0;
  for (int s = 0; s < ksplit; ++s) {           // ascending seg: ties -> lower k
    const float d = segDist[(size_t)s * NROWS + n];
    const int   i = segIdx [(size_t)s * NROWS + n];
    if (d < b) { b = d; bi = i; }
  }
  out[n] = bi;
}

extern "C" void kernel_launch(void* const* d_in, const int* in_sizes, int n_in,
                              void* d_out, int out_size, void* d_ws, size_t ws_size,
                              hipStream_t stream) {
  const float* x  = (const float*)d_in[0];   // [N, 64] fp32
  const float* cb = (const float*)d_in[1];   // [K, 64] fp32
  int* out = (int*)d_out;                    // [N] int32

  // Largest ksplit whose scratch fits (8 => 1024 blocks = 4/CU).
  const int candidates[4] = {8, 4, 2, 1};
  int ksplit = 1;
  for (int c = 0; c < 4; ++c) {
    const size_t need = (size_t)4 * KC + (size_t)8 * candidates[c] * NROWS;
    if (need <= ws_size) { ksplit = candidates[c]; break; }
  }

  float* csq     = (float*)d_ws;                         // K floats
  float* segDist = csq + KC;                             // ksplit*N floats
  int*   segIdx  = (int*)(segDist + (size_t)ksplit * NROWS);

  csq_kernel<<<dim3(KC / TPB), dim3(TPB), 0, stream>>>(cb, csq);
  vq_main_kernel<<<dim3(ROWBLKS, ksplit), dim3(TPB), 0, stream>>>(
      x, cb, csq, segDist, segIdx, ksplit);
  vq_reduce_kernel<<<dim3(NROWS / TPB), dim3(TPB), 0, stream>>>(
      segDist, segIdx, out, ksplit);
}

// Round 5
// 297.676 us; speedup vs baseline: 2.2616x; 2.2616x over previous
//
#include <hip/hip_runtime.h>
#include <math.h>

// VectorQuantizer: argmin_k ||x_n - c_k||^2, N=32768, K=8192, D=64, fp32.
// Round-5: bf16 3-way-split MFMA. Rounds 1-4 proved every fp32-VALU layout
// loses to the register allocator (48/76/64 VGPR remat+spill) and is floored
// at 218 us anyway. Here the cross term x.c^T runs on the matrix pipe:
// fp32 = a1+a2+a3 (bf16 planes, exact residual extraction, RNE), dot built
// from 6 MFMA products a1b1 + (a1b2+a2b1) + (a1b3+a2b2+a3b1) accumulated in
// one fp32 acc -> ~1e-6 abs dot error (< fmaf-chain reorder noise that has
// measured absmax 0 for 4 rounds). 206 G MFMA-FLOPs -> 82 us floor @ 2.5 PF.
//
// Block: 512 thr (8 waves), 64 rows. Waves 0-3 (group 0) own even 32-code
// tiles, waves 4-7 odd tiles: each iteration one group runs MFMA while the
// other splits+stages the next tile into the other LDS buffer (producer/
// consumer double-buffer, one barrier per tile). A-planes split once into
// LDS; per-wave A-frags live in 24 VGPRs. Argmin: packed (distbits<<32)|code
// u64 per C-slot, strict ascending-code updates + u64 mins everywhere =
// numpy first-occurrence tie-break (dists are ~tens, never negative, so
// float bit order = value order). dist = fmaf(-2,acc,xsq)+csq with xsq/csq
// from sequential-fmaf pre-kernels (identical chain to rounds 1-4).
// MFMA 16x16x32 layouts (measured m89/m91): A[m=lane&15][k=quad*8+j],
// B[n=lane&15][same k], C col=lane&15 row=quad*4+reg. LDS rows padded +8
// shorts (stride 144 B) -> balanced banks for ds_read_b128.

typedef __attribute__((ext_vector_type(8))) short s8v;
typedef __attribute__((ext_vector_type(4))) short s4v;
typedef __attribute__((ext_vector_type(4))) float f4v;

constexpr int NROWS = 32768;
constexpr int KC    = 8192;
constexpr int DD    = 64;
constexpr int BROWS = 64;                 // rows per block
constexpr int TPB   = 512;                // 8 waves
constexpr int BTILE = 32;                 // codes per tile
constexpr int NTILES = KC / BTILE;        // 256
constexpr int LSTR  = DD + 8;             // LDS row stride in shorts (pad)

__device__ __forceinline__ short bf16_rne(float v, float& resid) {
  unsigned u = __float_as_uint(v);
  unsigned r = (u + 0x7FFFu + ((u >> 16) & 1u)) >> 16;
  resid = v - __uint_as_float(r << 16);   // exact
  return (short)r;
}
__device__ __forceinline__ void split3(float v, short& b1, short& b2, short& b3) {
  float r1, r2, r3;
  b1 = bf16_rne(v, r1);
  b2 = bf16_rne(r1, r2);
  b3 = bf16_rne(r2, r3);
}

__global__ void csq_kernel(const float* __restrict__ cb, float* __restrict__ csq) {
  const int k = blockIdx.x * blockDim.x + threadIdx.x;
  const float* cp = cb + (size_t)k * DD;
  float s = 0.f;
#pragma unroll
  for (int d = 0; d < DD; ++d) s = fmaf(cp[d], cp[d], s);
  csq[k] = s;
}

__global__ void xsq_kernel(const float* __restrict__ x, float* __restrict__ xsq) {
  const int n = blockIdx.x * blockDim.x + threadIdx.x;
  const float* xp = x + (size_t)n * DD;
  float s = 0.f;
#pragma unroll
  for (int d = 0; d < DD; ++d) s = fmaf(xp[d], xp[d], s);
  xsq[n] = s;
}

__global__ __launch_bounds__(TPB, 4)
void vq_mfma_kernel(const float* __restrict__ x, const float* __restrict__ cb,
                    const float* __restrict__ csq_g, const float* __restrict__ xsq_g,
                    int* __restrict__ out) {
  __shared__ short lds_A[3][BROWS][LSTR];          // 27648 B
  __shared__ short lds_B[2][3][BTILE][LSTR];       // 27648 B
  __shared__ float lds_csq[2][BTILE];              // 256 B
  __shared__ unsigned long long lds_best[BROWS][2];// 1024 B

  const int tid   = threadIdx.x;
  const int lane  = tid & 63;
  const int w     = tid >> 6;          // wave 0..7
  const int wrow  = w & 3;             // row stripe (16 rows)
  const int group = tid >> 8;          // 0: even tiles, 1: odd tiles
  const int col   = lane & 15;
  const int q     = (lane >> 4) & 3;
  const int kq    = q * 8;             // k sub-offset within 32-chunk
  const int blockRow = blockIdx.x * BROWS;

  // ---- Prologue: stage A planes (split 64 rows x 64 d), 8 floats/thread.
  {
    const int row  = tid >> 3;               // 0..63
    const int koff = (tid & 7) * 8;          // 0..56
    const float* src = x + (size_t)(blockRow + row) * DD + koff;
    const float4 g0 = *(const float4*)(src);
    const float4 g1 = *(const float4*)(src + 4);
    float v[8] = {g0.x, g0.y, g0.z, g0.w, g1.x, g1.y, g1.z, g1.w};
    s8v p1, p2, p3;
#pragma unroll
    for (int e = 0; e < 8; ++e) { short a, b, c; split3(v[e], a, b, c);
      p1[e] = a; p2[e] = b; p3[e] = c; }
    *(s8v*)&lds_A[0][row][koff] = p1;
    *(s8v*)&lds_A[1][row][koff] = p2;
    *(s8v*)&lds_A[2][row][koff] = p3;
  }
  // ---- Stage B tile 0 into buf 0 (all 512 threads, 4 floats each).
  {
    const int code = tid >> 4;               // 0..31
    const int koff = (tid & 15) * 4;         // 0..60
    const float4 g = *(const float4*)(cb + (size_t)code * DD + koff);
    float v[4] = {g.x, g.y, g.z, g.w};
    s4v p1, p2, p3;
#pragma unroll
    for (int e = 0; e < 4; ++e) { short a, b, c; split3(v[e], a, b, c);
      p1[e] = a; p2[e] = b; p3[e] = c; }
    *(s4v*)&lds_B[0][0][code][koff] = p1;
    *(s4v*)&lds_B[0][1][code][koff] = p2;
    *(s4v*)&lds_B[0][2][code][koff] = p3;
    if (tid < BTILE) lds_csq[0][tid] = csq_g[tid];
  }

  // Per-lane xsq for this wave's 4 C-rows (row = wrow*16 + q*4 + i).
  const float4 xs4 = *(const float4*)(xsq_g + blockRow + wrow * 16 + q * 4);
  const float xsqr[4] = {xs4.x, xs4.y, xs4.z, xs4.w};

  __syncthreads();

  // A fragments: 3 planes x 2 K-chunks, 8 bf16 each = 24 VGPRs. Resident.
  s8v afr[3][2];
#pragma unroll
  for (int p = 0; p < 3; ++p)
#pragma unroll
    for (int h = 0; h < 2; ++h)
      afr[p][h] = *(const s8v*)&lds_A[p][wrow * 16 + col][h * 32 + kq];

  unsigned long long best[4] = {~0ull, ~0ull, ~0ull, ~0ull};

  // Term pairs (A-plane, B-plane), magnitude-descending.
  constexpr int PA[6] = {0, 0, 1, 0, 1, 2};
  constexpr int PB[6] = {0, 1, 0, 2, 1, 0};

  for (int t = 0; t < NTILES; ++t) {
    if ((t & 1) == group) {
      // ---- Compute tile t from buf (t&1).
      const int buf = t & 1;
      const int cbase = t * BTILE;
#pragma unroll
      for (int c = 0; c < 2; ++c) {                 // two 16-code chunks
        f4v acc = {0.f, 0.f, 0.f, 0.f};
#pragma unroll
        for (int pr = 0; pr < 6; ++pr) {
#pragma unroll
          for (int h = 0; h < 2; ++h) {
            const s8v bf = *(const s8v*)
                &lds_B[buf][PB[pr]][c * 16 + col][h * 32 + kq];
            acc = __builtin_amdgcn_mfma_f32_16x16x32_bf16(
                afr[PA[pr]][h], bf, acc, 0, 0, 0);
          }
        }
        const float cs = lds_csq[buf][c * 16 + col];
        const unsigned code = (unsigned)(cbase + c * 16 + col);
#pragma unroll
        for (int i = 0; i < 4; ++i) {
          const float dist = fmaf(-2.f, acc[i], xsqr[i]) + cs;
          const unsigned long long key =
              ((unsigned long long)__float_as_uint(dist) << 32) | code;
          if (key < best[i]) best[i] = key;
        }
      }
    } else if (t + 1 < NTILES) {
      // ---- Stage tile t+1 (this group's next) into buf ((t+1)&1).
      const int nb = (t + 1) & 1;
      const int st = tid & 255;
      const int code = st >> 3;                     // 0..31
      const int koff = (st & 7) * 8;                // 0..56
      const float* src = cb + (size_t)((t + 1) * BTILE + code) * DD + koff;
      const float4 g0 = *(const float4*)(src);
      const float4 g1 = *(const float4*)(src + 4);
      float v[8] = {g0.x, g0.y, g0.z, g0.w, g1.x, g1.y, g1.z, g1.w};
      s8v p1, p2, p3;
#pragma unroll
      for (int e = 0; e < 8; ++e) { short a, b, c; split3(v[e], a, b, c);
        p1[e] = a; p2[e] = b; p3[e] = c; }
      *(s8v*)&lds_B[nb][0][code][koff] = p1;
      *(s8v*)&lds_B[nb][1][code][koff] = p2;
      *(s8v*)&lds_B[nb][2][code][koff] = p3;
      if (st < BTILE) lds_csq[nb][st] = csq_g[(t + 1) * BTILE + st];
    }
    __syncthreads();
  }

  // ---- Reduce: butterfly over the 16 col-lanes (u64 min keeps lowest code
  // on exact ties), then cross-group min via LDS.
#pragma unroll
  for (int i = 0; i < 4; ++i) {
    unsigned long long b = best[i];
#pragma unroll
    for (int m = 1; m < 16; m <<= 1) {
      const unsigned long long o = __shfl_xor(b, m, 64);
      if (o < b) b = o;
    }
    if (col == 0) lds_best[wrow * 16 + q * 4 + i][group] = b;
  }
  __syncthreads();
  if (tid < BROWS) {
    const unsigned long long a = lds_best[tid][0];
    const unsigned long long b = lds_best[tid][1];
    out[blockRow + tid] = (int)(unsigned)((a < b ? a : b) & 0xFFFFFFFFull);
  }
}

extern "C" void kernel_launch(void* const* d_in, const int* in_sizes, int n_in,
                              void* d_out, int out_size, void* d_ws, size_t ws_size,
                              hipStream_t stream) {
  const float* x  = (const float*)d_in[0];   // [N, 64] fp32
  const float* cb = (const float*)d_in[1];   // [K, 64] fp32
  int* out = (int*)d_out;                    // [N] int32

  float* csq_g = (float*)d_ws;               // 8192 floats
  float* xsq_g = csq_g + KC;                 // 32768 floats  (total 160 KB)

  csq_kernel<<<dim3(KC / 256), dim3(256), 0, stream>>>(cb, csq_g);
  xsq_kernel<<<dim3(NROWS / 256), dim3(256), 0, stream>>>(x, xsq_g);
  vq_mfma_kernel<<<dim3(NROWS / BROWS), dim3(TPB), 0, stream>>>(
      x, cb, csq_g, xsq_g, out);
}

// Round 6
// 263.332 us; speedup vs baseline: 2.5566x; 1.1304x over previous
//
#include <hip/hip_runtime.h>
#include <math.h>

// VectorQuantizer: argmin_k ||x_n - c_k||^2, N=32768, K=8192, D=64, fp32.
// Round-6: 32x32x16 MFMA, pre-split codebook, conflict-free frag-ordered LDS.
//
// Round-5 losses fixed here:
//  * 2.5e7 bank conflicts: B now lives in LDS in exact frag-read order
//    (chunk = [sub][plane][kc], lane-linear 16 B each) -> ds_read_b128 with
//    consecutive lanes on consecutive banks. Zero conflicts by construction.
//  * VALUBusy 61% from per-block re-split of cb: a pre-kernel splits the
//    codebook ONCE into a 3 MB frag-ordered bf16 buffer (3 planes); main
//    kernel staging is a pure linear 24 KB copy per 64-code tile.
//  * MfmaUtil 34%: 32x32x16 (faster measured rate than 16x16, 2x rows/wave
//    per B-read). 2 independent acc chains cover MFMA latency at 2 w/SIMD.
// Numerics identical in kind to round-5 (passed, absmax 0): fp32 = 3 bf16
// planes (exact residuals), 6 products grouped magnitude-wise into 2 fp32
// MFMA chains, dist = fmaf(-2,acc,xsq)+csq, strict < ascending code,
// u64 (distbits<<32|code) mins for cross-lane ties = numpy first-occurrence.
// C/D layout (measured m74/m101): col=lane&31, row=(reg&3)+8*(reg>>2)+4*(lane>>5).

typedef __attribute__((ext_vector_type(8)))  short s8v;
typedef __attribute__((ext_vector_type(16))) float f16v;
typedef __attribute__((ext_vector_type(4)))  float f4v;

constexpr int NROWS = 32768;
constexpr int KC    = 8192;
constexpr int DD    = 64;
constexpr int TPB   = 256;                 // 4 waves
constexpr int BROWS = 64;                  // rows per block (2 stripes x 32)
constexpr int BTILE = 64;                  // codes per tile (2 x 32-code subtiles)
constexpr int NT    = KC / BTILE;          // 128 tiles
constexpr int TILE_SHORTS = 12288;         // 24 KB per tile in bSwz/ldsB

__device__ __forceinline__ short bf16_rne(float v, float& resid) {
  unsigned u = __float_as_uint(v);
  unsigned r = (u + 0x7FFFu + ((u >> 16) & 1u)) >> 16;
  resid = v - __uint_as_float(r << 16);   // exact
  return (short)r;
}
__device__ __forceinline__ void split3(float v, short& b1, short& b2, short& b3) {
  float r1, r2, r3;
  b1 = bf16_rne(v, r1);
  b2 = bf16_rne(r1, r2);
  b3 = bf16_rne(r2, r3);
}

// Pre-kernel: blocks [0,32): split cb -> frag-ordered bSwz + csq (sequential
// fmaf chain). blocks [32,160): xsq (sequential fmaf chain).
__global__ void vq_pre_kernel(const float* __restrict__ x,
                              const float* __restrict__ cb,
                              short* __restrict__ bSwz,
                              float* __restrict__ csq,
                              float* __restrict__ xsq) {
  const int bid = blockIdx.x, tid = threadIdx.x;
  if (bid < KC / TPB) {
    const int code = bid * TPB + tid;
    const float* cp = cb + (size_t)code * DD;
    float v[DD];
#pragma unroll
    for (int d = 0; d < DD; d += 4) {
      const float4 g = *(const float4*)(cp + d);
      v[d] = g.x; v[d + 1] = g.y; v[d + 2] = g.z; v[d + 3] = g.w;
    }
    float s = 0.f;
#pragma unroll
    for (int d = 0; d < DD; ++d) s = fmaf(v[d], v[d], s);
    csq[code] = s;
    short p1[DD], p2[DD], p3[DD];
#pragma unroll
    for (int d = 0; d < DD; ++d) split3(v[d], p1[d], p2[d], p3[d]);
    // 32-code group g, lane slot l; chunk (p,kc) holds 64 lanes x 8 bf16:
    // lane (h*32+l) = code (g*32+l), k = kc*16 + h*8 + j.
    const int g = code >> 5, l = code & 31;
    short* base = bSwz + (size_t)g * 6144;
#pragma unroll
    for (int p = 0; p < 3; ++p) {
      const short* pl = (p == 0) ? p1 : (p == 1) ? p2 : p3;
#pragma unroll
      for (int kc4 = 0; kc4 < 4; ++kc4)
#pragma unroll
        for (int h = 0; h < 2; ++h) {
          s8v wv;
#pragma unroll
          for (int j = 0; j < 8; ++j) wv[j] = pl[kc4 * 16 + h * 8 + j];
          *(s8v*)(base + (p * 4 + kc4) * 512 + (h * 32 + l) * 8) = wv;
        }
    }
  } else {
    const int n = (bid - KC / TPB) * TPB + tid;
    const float* xp = x + (size_t)n * DD;
    float s = 0.f;
#pragma unroll
    for (int d = 0; d < DD; ++d) s = fmaf(xp[d], xp[d], s);
    xsq[n] = s;
  }
}

__global__ __launch_bounds__(TPB, 2)
void vq_mfma_kernel(const float* __restrict__ x, const short* __restrict__ bSwz,
                    const float* __restrict__ csq_g, const float* __restrict__ xsq_g,
                    int* __restrict__ out) {
  __shared__ alignas(16) short ldsA[3][BROWS][DD];   // 24576 B
  __shared__ alignas(16) short ldsB[2][TILE_SHORTS]; // 49152 B
  __shared__ alignas(16) float ldsXsq[BROWS];        // 256 B
  __shared__ float ldsCsq[2][BTILE];                 // 512 B
  __shared__ unsigned long long ldsRed[BROWS][2];    // 1024 B

  const int tid  = threadIdx.x;
  const int lane = tid & 63;
  const int w    = tid >> 6;
  const int s    = w & 1;        // row stripe (32 rows)
  const int ch   = w >> 1;       // code half (32 codes)
  const int half = lane >> 5;
  const int col  = lane & 31;
  const int blockRow = blockIdx.x * BROWS;

  // ---- Stage A: split x rows into LDS planes (once per block).
  {
    const int row = tid >> 2, dseg = (tid & 3) * 16;
    const float* xp = x + (size_t)(blockRow + row) * DD + dseg;
    float v[16];
#pragma unroll
    for (int d = 0; d < 16; d += 4) {
      const float4 g = *(const float4*)(xp + d);
      v[d] = g.x; v[d + 1] = g.y; v[d + 2] = g.z; v[d + 3] = g.w;
    }
    short q1[16], q2[16], q3[16];
#pragma unroll
    for (int e = 0; e < 16; ++e) split3(v[e], q1[e], q2[e], q3[e]);
#pragma unroll
    for (int h2 = 0; h2 < 2; ++h2) {
      s8v a, b, c;
#pragma unroll
      for (int j = 0; j < 8; ++j) {
        a[j] = q1[h2 * 8 + j]; b[j] = q2[h2 * 8 + j]; c[j] = q3[h2 * 8 + j];
      }
      *(s8v*)&ldsA[0][row][dseg + h2 * 8] = a;
      *(s8v*)&ldsA[1][row][dseg + h2 * 8] = b;
      *(s8v*)&ldsA[2][row][dseg + h2 * 8] = c;
    }
  }
  if (tid < BROWS) ldsXsq[tid] = xsq_g[blockRow + tid];
  if (tid < BTILE) ldsCsq[0][tid] = csq_g[tid];
  // ---- Stage B tile 0 (linear 24 KB copy).
  {
    const float4* src = (const float4*)bSwz;
    float4* dst = (float4*)&ldsB[0][0];
#pragma unroll
    for (int seg = 0; seg < 6; ++seg) dst[seg * 256 + tid] = src[seg * 256 + tid];
  }
  __syncthreads();

  // ---- A fragments resident: 3 planes x 4 kchunks x 8 bf16 = 48 VGPR.
  s8v afr[3][4];
#pragma unroll
  for (int p = 0; p < 3; ++p)
#pragma unroll
    for (int kc4 = 0; kc4 < 4; ++kc4)
      afr[p][kc4] = *(const s8v*)&ldsA[p][s * 32 + col][kc4 * 16 + half * 8];

  // xsq for this lane's 16 C-slots: row = s*32 + (i&3) + 8*(i>>2) + 4*half.
  float xq[16];
  {
    const float* xb = &ldsXsq[s * 32 + 4 * half];
#pragma unroll
    for (int g8 = 0; g8 < 4; ++g8) {
      const f4v t4 = *(const f4v*)(xb + g8 * 8);
      xq[g8 * 4] = t4[0]; xq[g8 * 4 + 1] = t4[1];
      xq[g8 * 4 + 2] = t4[2]; xq[g8 * 4 + 3] = t4[3];
    }
  }

  float bestD[16];
  unsigned bestC[16];
#pragma unroll
  for (int i = 0; i < 16; ++i) { bestD[i] = INFINITY; bestC[i] = 0u; }

  // Chain A: (a1,b1),(a2,b1),(a2,b2); Chain B: (a1,b2),(a1,b3),(a3,b1).
  constexpr int PAA[3] = {0, 1, 1}, PBA[3] = {0, 0, 1};
  constexpr int PAB[3] = {0, 0, 2}, PBB[3] = {1, 2, 0};

  for (int t = 0; t < NT; ++t) {
    const int buf = t & 1;
    // Prefetch next tile into registers (lands during compute).
    float4 pf[6];
    if (t + 1 < NT) {
      const float4* src = (const float4*)(bSwz + (size_t)(t + 1) * TILE_SHORTS);
#pragma unroll
      for (int seg = 0; seg < 6; ++seg) pf[seg] = src[seg * 256 + tid];
      if (tid < BTILE) ldsCsq[buf ^ 1][tid] = csq_g[(t + 1) * BTILE + tid];
    }
    // B fragments: lane-linear b128, zero conflicts.
    s8v bfr[3][4];
#pragma unroll
    for (int p = 0; p < 3; ++p)
#pragma unroll
      for (int kc4 = 0; kc4 < 4; ++kc4)
        bfr[p][kc4] = *(const s8v*)
            &ldsB[buf][(ch * 12 + p * 4 + kc4) * 512 + lane * 8];

    f16v accA = {0.f,0.f,0.f,0.f,0.f,0.f,0.f,0.f,0.f,0.f,0.f,0.f,0.f,0.f,0.f,0.f};
    f16v accB = {0.f,0.f,0.f,0.f,0.f,0.f,0.f,0.f,0.f,0.f,0.f,0.f,0.f,0.f,0.f,0.f};
#pragma unroll
    for (int pr = 0; pr < 3; ++pr)
#pragma unroll
      for (int kc4 = 0; kc4 < 4; ++kc4) {
        accA = __builtin_amdgcn_mfma_f32_32x32x16_bf16(
            afr[PAA[pr]][kc4], bfr[PBA[pr]][kc4], accA, 0, 0, 0);
        accB = __builtin_amdgcn_mfma_f32_32x32x16_bf16(
            afr[PAB[pr]][kc4], bfr[PBB[pr]][kc4], accB, 0, 0, 0);
      }

    const float cs = ldsCsq[buf][ch * 32 + col];
    const unsigned code = (unsigned)(t * BTILE + ch * 32 + col);
#pragma unroll
    for (int i = 0; i < 16; ++i) {
      const float acc = accA[i] + accB[i];
      const float dist = fmaf(-2.f, acc, xq[i]) + cs;
      if (dist < bestD[i]) { bestD[i] = dist; bestC[i] = code; }  // first k wins
    }

    if (t + 1 < NT) {
      float4* dst = (float4*)&ldsB[buf ^ 1][0];
#pragma unroll
      for (int seg = 0; seg < 6; ++seg) dst[seg * 256 + tid] = pf[seg];
    }
    __syncthreads();
  }

  // ---- Reduce across the 32 col-lanes of each half (u64 min keeps lowest
  // code on exact ties), then across code-halves via LDS.
  unsigned long long key[16];
#pragma unroll
  for (int i = 0; i < 16; ++i)
    key[i] = ((unsigned long long)__float_as_uint(bestD[i]) << 32) | bestC[i];
#pragma unroll
  for (int i = 0; i < 16; ++i) {
#pragma unroll
    for (int m = 1; m < 32; m <<= 1) {
      const unsigned long long o = __shfl_xor(key[i], m, 64);
      if (o < key[i]) key[i] = o;
    }
  }
  if (col == 0) {
#pragma unroll
    for (int i = 0; i < 16; ++i) {
      const int row = s * 32 + (i & 3) + 8 * (i >> 2) + 4 * half;
      ldsRed[row][ch] = key[i];
    }
  }
  __syncthreads();
  if (tid < BROWS) {
    const unsigned long long a = ldsRed[tid][0];
    const unsigned long long b = ldsRed[tid][1];
    out[blockRow + tid] = (int)(unsigned)((a < b ? a : b) & 0xFFFFFFFFull);
  }
}

extern "C" void kernel_launch(void* const* d_in, const int* in_sizes, int n_in,
                              void* d_out, int out_size, void* d_ws, size_t ws_size,
                              hipStream_t stream) {
  const float* x  = (const float*)d_in[0];   // [N, 64] fp32
  const float* cb = (const float*)d_in[1];   // [K, 64] fp32
  int* out = (int*)d_out;                    // [N] int32

  // ws: bSwz (3 MB frag-ordered bf16 planes) | csq (32 KB) | xsq (128 KB)
  short* bSwz  = (short*)d_ws;
  float* csq_g = (float*)((char*)d_ws + (size_t)KC * DD * 3 * 2);
  float* xsq_g = csq_g + KC;

  vq_pre_kernel<<<dim3(KC / TPB + NROWS / TPB), dim3(TPB), 0, stream>>>(
      x, cb, bSwz, csq_g, xsq_g);
  vq_mfma_kernel<<<dim3(NROWS / BROWS), dim3(TPB), 0, stream>>>(
      x, bSwz, csq_g, xsq_g, out);
}